// Round 5
// baseline (60964.807 us; speedup 1.0000x reference)
//
#include <hip/hip_runtime.h>
#include <cstdint>

// DROP_MODE 3 = JAX partitionable threefry, bits = x0^x1  (VERIFIED r3: absmax 0.0039)

static constexpr int TDEC = 400, TENC = 300, NMEL = 80, NBLK = 256;
static constexpr int RING = 32;      // ah/dh/ctx ring depth
static constexpr int INVM = 15;      // ACQUIRE-invalidate every 16 steps

__device__ __forceinline__ uint2 threefry2x32(uint32_t k0, uint32_t k1,
                                              uint32_t x0, uint32_t x1) {
  uint32_t k2 = k0 ^ k1 ^ 0x1BD11BDAu;
  x0 += k0; x1 += k1;
#define TFR(r) { x0 += x1; x1 = (x1 << (r)) | (x1 >> (32 - (r))); x1 ^= x0; }
  TFR(13) TFR(15) TFR(26) TFR(6)
  x0 += k1; x1 += k2 + 1u;
  TFR(17) TFR(29) TFR(16) TFR(24)
  x0 += k2; x1 += k0 + 2u;
  TFR(13) TFR(15) TFR(26) TFR(6)
  x0 += k0; x1 += k1 + 3u;
  TFR(17) TFR(29) TFR(16) TFR(24)
  x0 += k1; x1 += k2 + 4u;
  TFR(13) TFR(15) TFR(26) TFR(6)
  x0 += k2; x1 += k0 + 5u;
#undef TFR
  return make_uint2(x0, x1);
}

__device__ __forceinline__ bool keep_mask(uint32_t key0, uint32_t key1, uint32_t idx) {
  uint2 o = threefry2x32(key0, key1, 0u, idx);
  uint32_t bits = o.x ^ o.y;
  float u = __uint_as_float((bits >> 9) | 0x3f800000u) - 1.0f;
  return u < 0.5f;
}

__device__ __forceinline__ float dot4(float4 w, float4 a) {
  return w.x * a.x + w.y * a.y + w.z * a.z + w.w * a.w;
}

// ---- coherence helpers -------------------------------------------------------
// bypass (LLC coherence point) store/load, relaxed
__device__ __forceinline__ void s_rel(float* p, float v) {
  __hip_atomic_store(p, v, __ATOMIC_RELAXED, __HIP_MEMORY_SCOPE_AGENT);
}
__device__ __forceinline__ float l_rel(const float* p) {
  return __hip_atomic_load(p, __ATOMIC_RELAXED, __HIP_MEMORY_SCOPE_AGENT);
}
__device__ __forceinline__ float nt_load(const float* p) {
  return __builtin_nontemporal_load(p);
}

// ---- flag-tree grid barrier ---------------------------------------------------
// release on arrive (drains this block's bypass stores to LLC before flagging);
// waiters poll relaxed; ACQUIRE (L1+L2 invalidate) only when inv==true.
__device__ __forceinline__ void gsync(int* arrive, int* release, int bno, bool inv) {
  __syncthreads();
  if (blockIdx.x == 0) {
    if (threadIdx.x > 0)
      while (__hip_atomic_load(&arrive[threadIdx.x * 32], __ATOMIC_RELAXED,
                               __HIP_MEMORY_SCOPE_AGENT) < bno)
        __builtin_amdgcn_s_sleep(1);
    __syncthreads();
    if (threadIdx.x < 8)
      __hip_atomic_store(&release[threadIdx.x * 32], bno, __ATOMIC_RELEASE,
                         __HIP_MEMORY_SCOPE_AGENT);
  } else {
    if (threadIdx.x == 0)
      __hip_atomic_store(&arrive[blockIdx.x * 32], bno, __ATOMIC_RELEASE,
                         __HIP_MEMORY_SCOPE_AGENT);
  }
  if (threadIdx.x == 0) {
    int* rel = &release[(blockIdx.x & 7) * 32];
    if (inv) {
      while (__hip_atomic_load(rel, __ATOMIC_ACQUIRE, __HIP_MEMORY_SCOPE_AGENT) < bno)
        __builtin_amdgcn_s_sleep(1);
    } else {
      while (__hip_atomic_load(rel, __ATOMIC_RELAXED, __HIP_MEMORY_SCOPE_AGENT) < bno)
        __builtin_amdgcn_s_sleep(1);
    }
  }
  __syncthreads();
}

// ---- prenet: all 400 steps precomputed (teacher forcing) ----------------------
template <int K>
__device__ __forceinline__ void prenet_layer(const float* in_lds, float* out_lds,
                                             float* out_g, const float* __restrict__ W,
                                             uint32_t key0, uint32_t key1, int b0) {
  const int tid = threadIdx.x;
  const int cgp = tid & 63, bg = tid >> 6;
  float acc[4][4];
#pragma unroll
  for (int cc = 0; cc < 4; ++cc)
#pragma unroll
    for (int rr = 0; rr < 4; ++rr) acc[cc][rr] = 0.f;
  const float4* W4 = (const float4*)W;
  const float4* in4 = (const float4*)in_lds;
  for (int k4 = 0; k4 < K / 4; ++k4) {
    float4 a[4];
#pragma unroll
    for (int rr = 0; rr < 4; ++rr) a[rr] = in4[(bg * 4 + rr) * (K / 4) + k4];
#pragma unroll
    for (int cc = 0; cc < 4; ++cc) {
      float4 w = W4[(cgp + 64 * cc) * (K / 4) + k4];
#pragma unroll
      for (int rr = 0; rr < 4; ++rr) acc[cc][rr] += dot4(w, a[rr]);
    }
  }
#pragma unroll
  for (int cc = 0; cc < 4; ++cc)
#pragma unroll
    for (int rr = 0; rr < 4; ++rr) {
      int c = cgp + 64 * cc, br = bg * 4 + rr;
      float val = fmaxf(acc[cc][rr], 0.f);
      val = keep_mask(key0, key1, (uint32_t)((b0 + br) * 256 + c)) ? val * 2.f : 0.f;
      if (out_lds) out_lds[br * 256 + c] = val;
      if (out_g) out_g[(b0 + br) * 256 + c] = val;
    }
  __syncthreads();
}

__global__ __launch_bounds__(256) void prenet_kernel(const float* __restrict__ mels,
                                                     const float* __restrict__ Wp0,
                                                     const float* __restrict__ Wp1,
                                                     const float* __restrict__ Wp2,
                                                     float* __restrict__ x_all) {
  __shared__ float bufA[16 * 256];
  __shared__ float bufB[16 * 256];
  const int t = blockIdx.x >> 1, b0 = (blockIdx.x & 1) * 16;
  const int tid = threadIdx.x;
  for (int i = tid; i < 16 * 80; i += 256) {
    int br = i / 80, k = i % 80;
    bufB[br * 80 + k] = (t == 0) ? 0.f : mels[((b0 + br) * TDEC + (t - 1)) * NMEL + k];
  }
  __syncthreads();
  uint2 k0v = threefry2x32(0u, 42u, 0u, (uint32_t)(t * 3 + 0));
  uint2 k1v = threefry2x32(0u, 42u, 0u, (uint32_t)(t * 3 + 1));
  uint2 k2v = threefry2x32(0u, 42u, 0u, (uint32_t)(t * 3 + 2));
  prenet_layer<80>(bufB, bufA, nullptr, Wp0, k0v.x, k0v.y, b0);
  prenet_layer<256>(bufA, bufB, nullptr, Wp1, k1v.x, k1v.y, b0);
  prenet_layer<256>(bufB, nullptr, x_all + t * 8192, Wp2, k2v.x, k2v.y, b0);
}

// ---- pmem = enc @ Wm.T ---------------------------------------------------------
__global__ __launch_bounds__(256) void pmem_kernel(const float* __restrict__ enc,
                                                   const float* __restrict__ Wm,
                                                   float* __restrict__ pmem) {
  const int b = blockIdx.x / 10, pc = blockIdx.x % 10;
  const int j = threadIdx.x & 127, ph = threadIdx.x >> 7;
  const float4* Wm4 = (const float4*)Wm;
  const float4* enc4 = (const float4*)enc + (size_t)(b * 300 + pc * 30 + ph * 15) * 128;
  float acc[15];
#pragma unroll
  for (int pp = 0; pp < 15; ++pp) acc[pp] = 0.f;
  for (int k4 = 0; k4 < 128; ++k4) {
    float4 w = Wm4[j * 128 + k4];
#pragma unroll
    for (int pp = 0; pp < 15; ++pp) acc[pp] += dot4(w, enc4[pp * 128 + k4]);
  }
#pragma unroll
  for (int pp = 0; pp < 15; ++pp)
    pmem[(size_t)(b * 300 + pc * 30 + ph * 15 + pp) * 128 + j] = acc[pp];
}

// ---- persistent decoder ---------------------------------------------------------
struct DecParams {
  const float* enc; const float* xall; const float* pmem;
  const int* lens;
  const float *Wiha, *Whha, *biha, *bhha;
  const float *Wihd, *Whhd, *bihd, *bhhd;
  const float *Wq, *Kloc, *Wl, *vv, *Wout, *bout, *Wg, *bg;
  float *ah, *dh, *ctx, *conv, *e;   // ah/dh/ctx: ring-32 x [32][512]; conv: ring-2 (bypass); e: single (bypass)
  int *arrive, *release;
  float *omel, *ogate, *oalign;
};

#define AW2_OFF 6144
#define T2_OFF 6804

template <int KIN>
__device__ __forceinline__ void gru_phase(const float4* __restrict__ A4, int a4n,
                                          const float4* __restrict__ B4,
                                          const float4* __restrict__ H4,
                                          const float* __restrict__ Wih,
                                          const float* __restrict__ Whh,
                                          const float* __restrict__ bih,
                                          const float* __restrict__ bhh,
                                          const float* __restrict__ hprev,
                                          float* __restrict__ hout,
                                          int idx0, float* lds) {
  const int tid = threadIdx.x;
  const int row = tid >> 3, seg = tid & 7;
  constexpr int K4I = KIN / 4;
  constexpr int SI = K4I / 8;
  const float4* Wih4 = (const float4*)Wih;
  const float4* Whh4 = (const float4*)Whh;
  float acc[24];
#pragma unroll
  for (int g = 0; g < 24; ++g) acc[g] = 0.f;
  for (int s = 0; s < SI; ++s) {
    int k4 = seg * SI + s;
    float4 a = (k4 < a4n) ? A4[row * a4n + k4] : B4[row * 128 + (k4 - a4n)];
#pragma unroll
    for (int gate = 0; gate < 3; ++gate)
#pragma unroll
      for (int i = 0; i < 4; ++i)
        acc[gate * 4 + i] += dot4(Wih4[(size_t)(gate * 512 + idx0 + i) * K4I + k4], a);
  }
  for (int s = 0; s < 16; ++s) {
    int k4 = seg * 16 + s;
    float4 a = H4[row * 128 + k4];
#pragma unroll
    for (int gate = 0; gate < 3; ++gate)
#pragma unroll
      for (int i = 0; i < 4; ++i)
        acc[12 + gate * 4 + i] += dot4(Whh4[(size_t)(gate * 512 + idx0 + i) * 128 + k4], a);
  }
#pragma unroll
  for (int g = 0; g < 24; ++g) lds[(g * 32 + row) * 8 + seg] = acc[g];
  __syncthreads();
  if (tid < 128) {
    int i = tid >> 5, r = tid & 31;
    float gi[3], gh[3];
#pragma unroll
    for (int gate = 0; gate < 3; ++gate) {
      float si = 0.f, sh = 0.f;
#pragma unroll
      for (int s = 0; s < 8; ++s) {
        si += lds[((gate * 4 + i) * 32 + r) * 8 + s];
        sh += lds[((12 + gate * 4 + i) * 32 + r) * 8 + s];
      }
      gi[gate] = si + bih[gate * 512 + idx0 + i];
      gh[gate] = sh + bhh[gate * 512 + idx0 + i];
    }
    float rr = 1.f / (1.f + expf(-(gi[0] + gh[0])));
    float zz = 1.f / (1.f + expf(-(gi[1] + gh[1])));
    float nn = tanhf(gi[2] + rr * gh[2]);
    float hp = hprev[r * 512 + idx0 + i];
    s_rel(&hout[r * 512 + idx0 + i], (1.f - zz) * nn + zz * hp);
  }
  __syncthreads();
}

__global__ __launch_bounds__(256) void decoder_kernel(DecParams P) {
  __shared__ float smem[8788];
  const int blk = blockIdx.x, tid = threadIdx.x;
  const int row = blk >> 3, s8 = blk & 7;
  float2* aw2 = (float2*)(smem + AW2_OFF);
  float2* t2f = (float2*)(smem + T2_OFF);
  int bno = 0;

  for (int i = tid; i < 330; i += 256) aw2[i] = make_float2(0.f, 0.f);
  for (int i = tid; i < 992; i += 256) {
    int f = i / 31, k = i % 31;
    t2f[i] = make_float2(P.Kloc[f * 62 + k], P.Kloc[f * 62 + 31 + k]);
  }
  __syncthreads();

  for (int tt = 0; tt <= TDEC; ++tt) {
    const int sc = tt & (RING - 1), s1 = (tt - 1) & (RING - 1), s2 = (tt - 2) & (RING - 1);
    float* ahC = P.ah + sc * 16384;
    const float* ahP = P.ah + s1 * 16384;
    const float* ctxP = P.ctx + s1 * 16384;
    float* dhW = P.dh + s1 * 16384;
    const float* dhP = P.dh + s2 * 16384;

    // -------- P1: attGRU_tt (blocks 0..127) || decGRU_{tt-1} (128..255) --------
    if (blk < 128) {
      if (tt < TDEC)
        gru_phase<768>((const float4*)(P.xall + (size_t)tt * 8192), 64,
                       (const float4*)ctxP, (const float4*)ahP,
                       P.Wiha, P.Whha, P.biha, P.bhha, ahP, ahC, blk * 4, smem);
    } else {
      if (tt >= 1)
        gru_phase<1024>((const float4*)ahP, 128, (const float4*)ctxP,
                        (const float4*)dhP, P.Wihd, P.Whhd, P.bihd, P.bhhd,
                        dhP, dhW, (blk - 128) * 4, smem);
    }
    gsync(P.arrive, P.release, ++bno, (tt & INVM) == 0);  // B1 (+rare L1/L2 inv)

    // -------- P2: energies + outproj_{tt-1} -------------------------------------
    if (tt < TDEC) {
      {  // q[row] = ah_tt[row] @ Wq.T
        int j = tid & 127, kh = tid >> 7;
        const float4* Wq4 = (const float4*)P.Wq;
        const float4* ah4 = (const float4*)ahC + row * 128;
        float p_ = 0.f;
        for (int k4 = kh * 64; k4 < kh * 64 + 64; ++k4) p_ += dot4(Wq4[j * 128 + k4], ah4[k4]);
        smem[j * 2 + kh] = p_;
      }
      __syncthreads();
      if (tid < 128) smem[256 + tid] = smem[tid * 2] + smem[tid * 2 + 1];
      __syncthreads();
      {
        int lane = tid & 63, pg = tid >> 6;
        const float* cvR = P.conv + (size_t)(tt & 1) * 307200;
        float wl0[32], wl1[32];
#pragma unroll
        for (int f = 0; f < 32; ++f) {
          wl0[f] = P.Wl[lane * 32 + f];
          wl1[f] = P.Wl[(lane + 64) * 32 + f];
        }
        float v0 = P.vv[lane], v1 = P.vv[lane + 64];
        float q0 = smem[256 + lane], q1 = smem[256 + lane + 64];
        int pbase = s8 * 38, pcount = min(38, TENC - pbase);
        int len = P.lens[row];
        for (int po = pg; po < pcount; po += 4) {
          int p = pbase + po;
          float a0 = 0.f, a1 = 0.f;
#pragma unroll
          for (int f = 0; f < 32; ++f) {
            float c = l_rel(&cvR[(size_t)(row * 32 + f) * 300 + p]);
            a0 += c * wl0[f];
            a1 += c * wl1[f];
          }
          float e0 = tanhf(q0 + P.pmem[(size_t)(row * 300 + p) * 128 + lane] + a0) * v0;
          float e1 = tanhf(q1 + P.pmem[(size_t)(row * 300 + p) * 128 + lane + 64] + a1) * v1;
          float es = e0 + e1;
#pragma unroll
          for (int off = 32; off > 0; off >>= 1) es += __shfl_xor(es, off, 64);
          if (lane == 0) s_rel(&P.e[row * 300 + p], (p < len) ? es : -1e9f);
        }
      }
    }
    if (tt >= 1) {  // outproj for step tt-1
      int kseg = tid & 31, g = tid >> 5;
      const float4* dh4 = (const float4*)dhW + row * 128;
      const float4* cx4 = (const float4*)ctxP + row * 128;
#pragma unroll
      for (int mi = 0; mi < 2; ++mi) {
        int m = s8 + 8 * g + 64 * mi;
        if (m <= 80) {
          const float4* W4 = (m < 80) ? ((const float4*)P.Wout + (size_t)m * 256)
                                      : (const float4*)P.Wg;
          float a = 0.f;
          for (int k4 = kseg * 8; k4 < kseg * 8 + 8; ++k4) {
            float4 x = (k4 < 128) ? dh4[k4] : cx4[k4 - 128];
            a += dot4(W4[k4], x);
          }
          smem[1600 + m * 32 + kseg] = a;
        }
      }
      __syncthreads();
      if (tid <= 80 && (tid & 7) == s8) {
        float sum = 0.f;
#pragma unroll
        for (int k = 0; k < 32; ++k) sum += smem[1600 + tid * 32 + k];
        if (tid < 80) P.omel[(size_t)(row * 80 + tid) * 400 + (tt - 1)] = sum + P.bout[tid];
        else P.ogate[row * 400 + (tt - 1)] = sum + P.bg[0];
      }
      __syncthreads();
    }
    if (tt == TDEC) break;
    gsync(P.arrive, P.release, ++bno, false);  // B2

    // -------- P3: softmax + ctx + conv_{tt+1}, per (row, s8) --------------------
    {
      float* e_l = smem;          // 300
      float* red = smem + 304;    // 4
      float* cpart = smem + 320;  // 256
      for (int i = tid; i < 300; i += 256) e_l[i] = l_rel(&P.e[row * 300 + i]);
      __syncthreads();
      float mx = -3.4e38f;
      for (int i = tid; i < 300; i += 256) mx = fmaxf(mx, e_l[i]);
#pragma unroll
      for (int off = 32; off > 0; off >>= 1) mx = fmaxf(mx, __shfl_xor(mx, off, 64));
      if ((tid & 63) == 0) red[tid >> 6] = mx;
      __syncthreads();
      mx = fmaxf(fmaxf(red[0], red[1]), fmaxf(red[2], red[3]));
      __syncthreads();
      float lsum = 0.f;
      for (int i = tid; i < 300; i += 256) {
        float ex = expf(e_l[i] - mx);
        e_l[i] = ex;
        lsum += ex;
      }
#pragma unroll
      for (int off = 32; off > 0; off >>= 1) lsum += __shfl_xor(lsum, off, 64);
      if ((tid & 63) == 0) red[tid >> 6] = lsum;
      __syncthreads();
      float inv = 1.f / (red[0] + red[1] + red[2] + red[3]);
      for (int i = tid; i < 300; i += 256) {
        float a = e_l[i] * inv;
        float ns = aw2[15 + i].y + a;
        aw2[15 + i] = make_float2(a, ns);
        if (s8 == 0) P.oalign[(size_t)(row * 400 + tt) * 300 + i] = a;
      }
      __syncthreads();
      {  // ctx partial: enc streamed NT (no L2 allocation)
        int j = tid & 63, pc = tid >> 6;
        float cp = 0.f;
        const float* ebase = P.enc + (size_t)(row * 300) * 512 + s8 * 64 + j;
        for (int p = pc * 75; p < pc * 75 + 75; ++p)
          cp += aw2[15 + p].x * nt_load(ebase + (size_t)p * 512);
        cpart[pc * 64 + j] = cp;
      }
      {  // location conv for step tt+1: one filter per wave, taps in registers
        int w = tid >> 6, lane = tid & 63;
        int f = s8 * 4 + w;
        float2 t2[31];
#pragma unroll
        for (int k = 0; k < 31; ++k) t2[k] = t2f[f * 31 + k];
        float* cw = P.conv + (size_t)((tt + 1) & 1) * 307200 + (size_t)(row * 32 + f) * 300;
        for (int i = lane; i < 300; i += 64) {
          float a = 0.f;
#pragma unroll
          for (int k = 0; k < 31; ++k) {
            float2 v = aw2[i + k];
            a += v.x * t2[k].x + v.y * t2[k].y;
          }
          s_rel(&cw[i], a);
        }
      }
      __syncthreads();
      if (tid < 64) {
        float* ctxC = P.ctx + sc * 16384;
        s_rel(&ctxC[row * 512 + s8 * 64 + tid],
              cpart[tid] + cpart[64 + tid] + cpart[128 + tid] + cpart[192 + tid]);
      }
    }
    gsync(P.arrive, P.release, ++bno, false);  // B3
  }
}

// ---- host ---------------------------------------------------------------------
extern "C" void kernel_launch(void* const* d_in, const int* in_sizes, int n_in,
                              void* d_out, int out_size, void* d_ws, size_t ws_size,
                              hipStream_t stream) {
  const float* enc = (const float*)d_in[0];
  const float* mels = (const float*)d_in[1];
  const int* lens = (const int*)d_in[2];
  const float* Wp0 = (const float*)d_in[3];
  const float* Wp1 = (const float*)d_in[4];
  const float* Wp2 = (const float*)d_in[5];
  const float* Wiha = (const float*)d_in[6];
  const float* Whha = (const float*)d_in[7];
  const float* biha = (const float*)d_in[8];
  const float* bhha = (const float*)d_in[9];
  const float* Wihd = (const float*)d_in[10];
  const float* Whhd = (const float*)d_in[11];
  const float* bihd = (const float*)d_in[12];
  const float* bhhd = (const float*)d_in[13];
  const float* Wq = (const float*)d_in[14];
  const float* Wm = (const float*)d_in[15];
  const float* Kloc = (const float*)d_in[16];
  const float* Wl = (const float*)d_in[17];
  const float* vv = (const float*)d_in[18];
  const float* Wout = (const float*)d_in[19];
  const float* bout = (const float*)d_in[20];
  const float* Wg = (const float*)d_in[21];
  const float* bg = (const float*)d_in[22];

  float* ws = (float*)d_ws;
  float* x_all = ws;                    // 3,276,800
  float* pmem = x_all + 3276800;        // 1,228,800
  float* ah = pmem + 1228800;           // ring32: 524,288
  float* dh = ah + 524288;              // 524,288
  float* ctx = dh + 524288;             // 524,288
  float* e = ctx + 524288;              // 9,600
  float* conv = e + 9600;               // ring2: 614,400
  int* arrive = (int*)(conv + 614400);  // 8,192 ints
  int* release = arrive + 8192;         // 256 ints

  (void)hipMemsetAsync(ah + (RING - 1) * 16384, 0, 16384 * sizeof(float), stream);
  (void)hipMemsetAsync(dh + (RING - 1) * 16384, 0, 16384 * sizeof(float), stream);
  (void)hipMemsetAsync(ctx + (RING - 1) * 16384, 0, 16384 * sizeof(float), stream);
  (void)hipMemsetAsync(conv, 0, 307200 * sizeof(float), stream);
  (void)hipMemsetAsync(arrive, 0, (8192 + 256) * sizeof(int), stream);

  prenet_kernel<<<800, 256, 0, stream>>>(mels, Wp0, Wp1, Wp2, x_all);
  pmem_kernel<<<320, 256, 0, stream>>>(enc, Wm, pmem);

  float* omel = (float*)d_out;                  // [32][80][400]
  float* ogate = omel + 32 * 80 * 400;          // [32][400]
  float* oalign = ogate + 32 * 400;             // [32][400][300]

  DecParams P;
  P.enc = enc; P.xall = x_all; P.pmem = pmem; P.lens = lens;
  P.Wiha = Wiha; P.Whha = Whha; P.biha = biha; P.bhha = bhha;
  P.Wihd = Wihd; P.Whhd = Whhd; P.bihd = bihd; P.bhhd = bhhd;
  P.Wq = Wq; P.Kloc = Kloc; P.Wl = Wl; P.vv = vv;
  P.Wout = Wout; P.bout = bout; P.Wg = Wg; P.bg = bg;
  P.ah = ah; P.dh = dh; P.ctx = ctx; P.conv = conv; P.e = e;
  P.arrive = arrive; P.release = release;
  P.omel = omel; P.ogate = ogate; P.oalign = oalign;

  decoder_kernel<<<NBLK, 256, 0, stream>>>(P);
}

// Round 6
// 54585.687 us; speedup vs baseline: 1.1169x; 1.1169x over previous
//
#include <hip/hip_runtime.h>
#include <cstdint>

// DROP_MODE 3 = JAX partitionable threefry, bits = x0^x1  (VERIFIED r3+: absmax 0.0039)

static constexpr int TDEC = 400, TENC = 300, NMEL = 80, NBLK = 256;
static constexpr int RING = 32;      // ah/dh/ctx ring depth
static constexpr int INVM = 15;      // ACQUIRE-invalidate every 16 steps

__device__ __forceinline__ uint2 threefry2x32(uint32_t k0, uint32_t k1,
                                              uint32_t x0, uint32_t x1) {
  uint32_t k2 = k0 ^ k1 ^ 0x1BD11BDAu;
  x0 += k0; x1 += k1;
#define TFR(r) { x0 += x1; x1 = (x1 << (r)) | (x1 >> (32 - (r))); x1 ^= x0; }
  TFR(13) TFR(15) TFR(26) TFR(6)
  x0 += k1; x1 += k2 + 1u;
  TFR(17) TFR(29) TFR(16) TFR(24)
  x0 += k2; x1 += k0 + 2u;
  TFR(13) TFR(15) TFR(26) TFR(6)
  x0 += k0; x1 += k1 + 3u;
  TFR(17) TFR(29) TFR(16) TFR(24)
  x0 += k1; x1 += k2 + 4u;
  TFR(13) TFR(15) TFR(26) TFR(6)
  x0 += k2; x1 += k0 + 5u;
#undef TFR
  return make_uint2(x0, x1);
}

__device__ __forceinline__ bool keep_mask(uint32_t key0, uint32_t key1, uint32_t idx) {
  uint2 o = threefry2x32(key0, key1, 0u, idx);
  uint32_t bits = o.x ^ o.y;
  float u = __uint_as_float((bits >> 9) | 0x3f800000u) - 1.0f;
  return u < 0.5f;
}

__device__ __forceinline__ float dot4(float4 w, float4 a) {
  return w.x * a.x + w.y * a.y + w.z * a.z + w.w * a.w;
}

// ---- coherence helpers -------------------------------------------------------
__device__ __forceinline__ void s_rel(float* p, float v) {
  __hip_atomic_store(p, v, __ATOMIC_RELAXED, __HIP_MEMORY_SCOPE_AGENT);
}
__device__ __forceinline__ float l_rel(const float* p) {
  return __hip_atomic_load(p, __ATOMIC_RELAXED, __HIP_MEMORY_SCOPE_AGENT);
}
__device__ __forceinline__ float nt_load(const float* p) {
  return __builtin_nontemporal_load(p);
}

// ---- global flag-tree barrier (r5-validated) --------------------------------
__device__ __forceinline__ void gsync(int* arrive, int* release, int bno, bool inv) {
  __syncthreads();
  if (blockIdx.x == 0) {
    if (threadIdx.x > 0)
      while (__hip_atomic_load(&arrive[threadIdx.x * 32], __ATOMIC_RELAXED,
                               __HIP_MEMORY_SCOPE_AGENT) < bno)
        __builtin_amdgcn_s_sleep(1);
    __syncthreads();
    if (threadIdx.x < 8)
      __hip_atomic_store(&release[threadIdx.x * 32], bno, __ATOMIC_RELEASE,
                         __HIP_MEMORY_SCOPE_AGENT);
  } else {
    if (threadIdx.x == 0)
      __hip_atomic_store(&arrive[blockIdx.x * 32], bno, __ATOMIC_RELEASE,
                         __HIP_MEMORY_SCOPE_AGENT);
  }
  if (threadIdx.x == 0) {
    int* rel = &release[(blockIdx.x & 7) * 32];
    if (inv) {
      while (__hip_atomic_load(rel, __ATOMIC_ACQUIRE, __HIP_MEMORY_SCOPE_AGENT) < bno)
        __builtin_amdgcn_s_sleep(1);
    } else {
      while (__hip_atomic_load(rel, __ATOMIC_RELAXED, __HIP_MEMORY_SCOPE_AGENT) < bno)
        __builtin_amdgcn_s_sleep(1);
    }
  }
  __syncthreads();
}

// ---- per-row 8-block barrier -------------------------------------------------
__device__ __forceinline__ void rsync(int* rarr, int* rrel, int row, int s8, int val) {
  __syncthreads();
  if (s8 == 0) {
    if (threadIdx.x < 7)
      while (__hip_atomic_load(&rarr[(row * 8 + 1 + threadIdx.x) * 32], __ATOMIC_RELAXED,
                               __HIP_MEMORY_SCOPE_AGENT) < val)
        __builtin_amdgcn_s_sleep(1);
    __syncthreads();
    if (threadIdx.x == 0)
      __hip_atomic_store(&rrel[row * 32], val, __ATOMIC_RELEASE, __HIP_MEMORY_SCOPE_AGENT);
  } else {
    if (threadIdx.x == 0) {
      __hip_atomic_store(&rarr[(row * 8 + s8) * 32], val, __ATOMIC_RELEASE,
                         __HIP_MEMORY_SCOPE_AGENT);
      while (__hip_atomic_load(&rrel[row * 32], __ATOMIC_RELAXED,
                               __HIP_MEMORY_SCOPE_AGENT) < val)
        __builtin_amdgcn_s_sleep(1);
    }
  }
  __syncthreads();
}

// ---- prenet (teacher-forced, all 400 steps parallel) ------------------------
template <int K>
__device__ __forceinline__ void prenet_layer(const float* in_lds, float* out_lds,
                                             float* out_g, const float* __restrict__ W,
                                             uint32_t key0, uint32_t key1, int b0) {
  const int tid = threadIdx.x;
  const int cgp = tid & 63, bg = tid >> 6;
  float acc[4][4];
#pragma unroll
  for (int cc = 0; cc < 4; ++cc)
#pragma unroll
    for (int rr = 0; rr < 4; ++rr) acc[cc][rr] = 0.f;
  const float4* W4 = (const float4*)W;
  const float4* in4 = (const float4*)in_lds;
  for (int k4 = 0; k4 < K / 4; ++k4) {
    float4 a[4];
#pragma unroll
    for (int rr = 0; rr < 4; ++rr) a[rr] = in4[(bg * 4 + rr) * (K / 4) + k4];
#pragma unroll
    for (int cc = 0; cc < 4; ++cc) {
      float4 w = W4[(cgp + 64 * cc) * (K / 4) + k4];
#pragma unroll
      for (int rr = 0; rr < 4; ++rr) acc[cc][rr] += dot4(w, a[rr]);
    }
  }
#pragma unroll
  for (int cc = 0; cc < 4; ++cc)
#pragma unroll
    for (int rr = 0; rr < 4; ++rr) {
      int c = cgp + 64 * cc, br = bg * 4 + rr;
      float val = fmaxf(acc[cc][rr], 0.f);
      val = keep_mask(key0, key1, (uint32_t)((b0 + br) * 256 + c)) ? val * 2.f : 0.f;
      if (out_lds) out_lds[br * 256 + c] = val;
      if (out_g) out_g[(b0 + br) * 256 + c] = val;
    }
  __syncthreads();
}

__global__ __launch_bounds__(256) void prenet_kernel(const float* __restrict__ mels,
                                                     const float* __restrict__ Wp0,
                                                     const float* __restrict__ Wp1,
                                                     const float* __restrict__ Wp2,
                                                     float* __restrict__ x_all) {
  __shared__ float bufA[16 * 256];
  __shared__ float bufB[16 * 256];
  const int t = blockIdx.x >> 1, b0 = (blockIdx.x & 1) * 16;
  const int tid = threadIdx.x;
  for (int i = tid; i < 16 * 80; i += 256) {
    int br = i / 80, k = i % 80;
    bufB[br * 80 + k] = (t == 0) ? 0.f : mels[((b0 + br) * TDEC + (t - 1)) * NMEL + k];
  }
  __syncthreads();
  uint2 k0v = threefry2x32(0u, 42u, 0u, (uint32_t)(t * 3 + 0));
  uint2 k1v = threefry2x32(0u, 42u, 0u, (uint32_t)(t * 3 + 1));
  uint2 k2v = threefry2x32(0u, 42u, 0u, (uint32_t)(t * 3 + 2));
  prenet_layer<80>(bufB, bufA, nullptr, Wp0, k0v.x, k0v.y, b0);
  prenet_layer<256>(bufA, bufB, nullptr, Wp1, k1v.x, k1v.y, b0);
  prenet_layer<256>(bufB, nullptr, x_all + t * 8192, Wp2, k2v.x, k2v.y, b0);
}

// ---- pmem = enc @ Wm.T -------------------------------------------------------
__global__ __launch_bounds__(256) void pmem_kernel(const float* __restrict__ enc,
                                                   const float* __restrict__ Wm,
                                                   float* __restrict__ pmem) {
  const int b = blockIdx.x / 10, pc = blockIdx.x % 10;
  const int j = threadIdx.x & 127, ph = threadIdx.x >> 7;
  const float4* Wm4 = (const float4*)Wm;
  const float4* enc4 = (const float4*)enc + (size_t)(b * 300 + pc * 30 + ph * 15) * 128;
  float acc[15];
#pragma unroll
  for (int pp = 0; pp < 15; ++pp) acc[pp] = 0.f;
  for (int k4 = 0; k4 < 128; ++k4) {
    float4 w = Wm4[j * 128 + k4];
#pragma unroll
    for (int pp = 0; pp < 15; ++pp) acc[pp] += dot4(w, enc4[pp * 128 + k4]);
  }
#pragma unroll
  for (int pp = 0; pp < 15; ++pp)
    pmem[(size_t)(b * 300 + pc * 30 + ph * 15 + pp) * 128 + j] = acc[pp];
}

// ---- persistent decoder ------------------------------------------------------
struct DecParams {
  const float* enc; const float* xall; const float* pmem;
  const int* lens;
  const float *Wiha, *Whha, *biha, *bhha;
  const float *Wihd, *Whhd, *bihd, *bhhd;
  const float *Wq, *Kloc, *Wl, *vv, *Wout, *bout, *Wg, *bg;
  float *ah, *dh, *ctx, *e;        // ah/dh/ctx: ring-32 x [32][512] (bypass-write); e: bypass
  int *arrive, *release, *rarr, *rrel;
  float *omel, *ogate, *oalign;
};

// LDS floats: [0..6143] scratch | [6144..6803] aw2 (330 f2) | [6804..8787] taps (992 f2)
//             [8788..10003] conv_l [32][38]
#define AW2_OFF 6144
#define T2_OFF 6804
#define CV_OFF 8788

template <int KIN>
__device__ __forceinline__ void gru_phase(const float4* __restrict__ A4, int a4n,
                                          const float4* __restrict__ B4,
                                          const float4* __restrict__ H4,
                                          const float* __restrict__ Wih,
                                          const float* __restrict__ Whh,
                                          const float* __restrict__ bih,
                                          const float* __restrict__ bhh,
                                          const float* __restrict__ hprev,
                                          float* __restrict__ hout,
                                          int idx0, float* lds) {
  const int tid = threadIdx.x;
  const int row = tid >> 3, seg = tid & 7;
  constexpr int K4I = KIN / 4;
  constexpr int SI = K4I / 8;
  const float4* Wih4 = (const float4*)Wih;
  const float4* Whh4 = (const float4*)Whh;
  float acc[24];
#pragma unroll
  for (int g = 0; g < 24; ++g) acc[g] = 0.f;
  for (int s = 0; s < SI; ++s) {
    int k4 = seg * SI + s;
    float4 a = (k4 < a4n) ? A4[row * a4n + k4] : B4[row * 128 + (k4 - a4n)];
#pragma unroll
    for (int gate = 0; gate < 3; ++gate)
#pragma unroll
      for (int i = 0; i < 4; ++i)
        acc[gate * 4 + i] += dot4(Wih4[(size_t)(gate * 512 + idx0 + i) * K4I + k4], a);
  }
  for (int s = 0; s < 16; ++s) {
    int k4 = seg * 16 + s;
    float4 a = H4[row * 128 + k4];
#pragma unroll
    for (int gate = 0; gate < 3; ++gate)
#pragma unroll
      for (int i = 0; i < 4; ++i)
        acc[12 + gate * 4 + i] += dot4(Whh4[(size_t)(gate * 512 + idx0 + i) * 128 + k4], a);
  }
#pragma unroll
  for (int g = 0; g < 24; ++g) lds[(g * 32 + row) * 8 + seg] = acc[g];
  __syncthreads();
  if (tid < 128) {
    int i = tid >> 5, r = tid & 31;
    float gi[3], gh[3];
#pragma unroll
    for (int gate = 0; gate < 3; ++gate) {
      float si = 0.f, sh = 0.f;
#pragma unroll
      for (int s = 0; s < 8; ++s) {
        si += lds[((gate * 4 + i) * 32 + r) * 8 + s];
        sh += lds[((12 + gate * 4 + i) * 32 + r) * 8 + s];
      }
      gi[gate] = si + bih[gate * 512 + idx0 + i];
      gh[gate] = sh + bhh[gate * 512 + idx0 + i];
    }
    float rr = 1.f / (1.f + expf(-(gi[0] + gh[0])));
    float zz = 1.f / (1.f + expf(-(gi[1] + gh[1])));
    float nn = tanhf(gi[2] + rr * gh[2]);
    float hp = hprev[r * 512 + idx0 + i];
    s_rel(&hout[r * 512 + idx0 + i], (1.f - zz) * nn + zz * hp);
  }
  __syncthreads();
}

__global__ __launch_bounds__(256) void decoder_kernel(DecParams P) {
  __shared__ float smem[10004];
  const int blk = blockIdx.x, tid = threadIdx.x;
  const int row = blk >> 3, s8 = blk & 7;
  float2* aw2 = (float2*)(smem + AW2_OFF);
  float2* t2f = (float2*)(smem + T2_OFF);
  float* conv_l = smem + CV_OFF;
  int bno = 0;
  const int pbase = s8 * 38, pcount = min(38, TENC - pbase);

  for (int i = tid; i < 330; i += 256) aw2[i] = make_float2(0.f, 0.f);
  for (int i = tid; i < 992; i += 256) {
    int f = i / 31, k = i % 31;
    t2f[i] = make_float2(P.Kloc[f * 62 + k], P.Kloc[f * 62 + 31 + k]);
  }
  __syncthreads();

  for (int tt = 0; tt <= TDEC; ++tt) {
    const int sc = tt & (RING - 1), s1 = (tt - 1) & (RING - 1), s2 = (tt - 2) & (RING - 1);
    float* ahC = P.ah + sc * 16384;
    const float* ahP = P.ah + s1 * 16384;
    const float* ctxP = P.ctx + s1 * 16384;
    float* dhW = P.dh + s1 * 16384;
    const float* dhP = P.dh + s2 * 16384;

    // ===== A: GRUs (role-split) + local conv (overlaps barrier wait) =========
    if (blk < 128) {
      if (tt < TDEC)
        gru_phase<768>((const float4*)(P.xall + (size_t)tt * 8192), 64,
                       (const float4*)ctxP, (const float4*)ahP,
                       P.Wiha, P.Whha, P.biha, P.bhha, ahP, ahC, blk * 4, smem);
    } else {
      if (tt >= 1)
        gru_phase<1024>((const float4*)ahP, 128, (const float4*)ctxP,
                        (const float4*)dhP, P.Wihd, P.Whhd, P.bihd, P.bhhd,
                        dhP, dhW, (blk - 128) * 4, smem);
    }
    if (tt < TDEC) {  // conv for THIS step's energies, purely from LDS state
      int f = tid >> 3, po0 = tid & 7;
      for (int po = po0; po < pcount; po += 8) {
        int p = pbase + po;
        float a = 0.f;
#pragma unroll
        for (int k = 0; k < 31; ++k) {
          float2 v = aw2[p + k];
          float2 t = t2f[f * 31 + k];
          a += v.x * t.x + v.y * t.y;
        }
        conv_l[f * 38 + po] = a;
      }
    }
    gsync(P.arrive, P.release, ++bno, (tt & INVM) == 0);  // B1 (global)

    // ===== B: q-proj + energies (e bypass-stores) ============================
    if (tt < TDEC) {
      {
        int j = tid & 127, kh = tid >> 7;
        const float4* Wq4 = (const float4*)P.Wq;
        const float4* ah4 = (const float4*)ahC + row * 128;
        float p_ = 0.f;
        for (int k4 = kh * 64; k4 < kh * 64 + 64; ++k4) p_ += dot4(Wq4[j * 128 + k4], ah4[k4]);
        smem[j * 2 + kh] = p_;
      }
      __syncthreads();
      if (tid < 128) smem[256 + tid] = smem[tid * 2] + smem[tid * 2 + 1];
      __syncthreads();
      {
        int lane = tid & 63, pg = tid >> 6;
        float wl0[32], wl1[32];
#pragma unroll
        for (int f = 0; f < 32; ++f) {
          wl0[f] = P.Wl[lane * 32 + f];
          wl1[f] = P.Wl[(lane + 64) * 32 + f];
        }
        float v0 = P.vv[lane], v1 = P.vv[lane + 64];
        float q0 = smem[256 + lane], q1 = smem[256 + lane + 64];
        int len = P.lens[row];
        for (int po = pg; po < pcount; po += 4) {
          int p = pbase + po;
          float a0 = 0.f, a1 = 0.f;
#pragma unroll
          for (int f = 0; f < 32; ++f) {
            float c = conv_l[f * 38 + po];  // LDS broadcast
            a0 += c * wl0[f];
            a1 += c * wl1[f];
          }
          float e0 = tanhf(q0 + P.pmem[(size_t)(row * 300 + p) * 128 + lane] + a0) * v0;
          float e1 = tanhf(q1 + P.pmem[(size_t)(row * 300 + p) * 128 + lane + 64] + a1) * v1;
          float es = e0 + e1;
#pragma unroll
          for (int off = 32; off > 0; off >>= 1) es += __shfl_xor(es, off, 64);
          if (lane == 0) s_rel(&P.e[row * 300 + p], (p < len) ? es : -1e9f);
        }
      }
      rsync(P.rarr, P.rrel, row, s8, tt + 1);  // B2 (per-row, 8 blocks)
    }

    // ===== C: e-prefetch || outproj(tt-1), then softmax+ctx ==================
    float ev0 = 0.f, ev1 = 0.f;
    if (tt < TDEC) {
      ev0 = l_rel(&P.e[row * 300 + tid]);
      if (tid < 44) ev1 = l_rel(&P.e[row * 300 + 256 + tid]);
    }
    if (tt >= 1) {  // outproj for step tt-1 (overlaps e-load latency)
      int kseg = tid & 31, g = tid >> 5;
      const float4* dh4 = (const float4*)dhW + row * 128;
      const float4* cx4 = (const float4*)ctxP + row * 128;
#pragma unroll
      for (int mi = 0; mi < 2; ++mi) {
        int m = s8 + 8 * g + 64 * mi;
        if (m <= 80) {
          const float4* W4 = (m < 80) ? ((const float4*)P.Wout + (size_t)m * 256)
                                      : (const float4*)P.Wg;
          float a = 0.f;
          for (int k4 = kseg * 8; k4 < kseg * 8 + 8; ++k4) {
            float4 x = (k4 < 128) ? dh4[k4] : cx4[k4 - 128];
            a += dot4(W4[k4], x);
          }
          smem[1600 + m * 32 + kseg] = a;
        }
      }
      __syncthreads();
      if (tid <= 80 && (tid & 7) == s8) {
        float sum = 0.f;
#pragma unroll
        for (int k = 0; k < 32; ++k) sum += smem[1600 + tid * 32 + k];
        if (tid < 80) P.omel[(size_t)(row * 80 + tid) * 400 + (tt - 1)] = sum + P.bout[tid];
        else P.ogate[row * 400 + (tt - 1)] = sum + P.bg[0];
      }
      __syncthreads();
    }
    if (tt == TDEC) break;
    {
      float* e_l = smem;          // 300
      float* red = smem + 304;    // 4
      float* cpart = smem + 320;  // 256
      e_l[tid] = ev0;
      if (tid < 44) e_l[256 + tid] = ev1;
      __syncthreads();
      float mx = -3.4e38f;
      for (int i = tid; i < 300; i += 256) mx = fmaxf(mx, e_l[i]);
#pragma unroll
      for (int off = 32; off > 0; off >>= 1) mx = fmaxf(mx, __shfl_xor(mx, off, 64));
      if ((tid & 63) == 0) red[tid >> 6] = mx;
      __syncthreads();
      mx = fmaxf(fmaxf(red[0], red[1]), fmaxf(red[2], red[3]));
      __syncthreads();
      float lsum = 0.f;
      for (int i = tid; i < 300; i += 256) {
        float ex = expf(e_l[i] - mx);
        e_l[i] = ex;
        lsum += ex;
      }
#pragma unroll
      for (int off = 32; off > 0; off >>= 1) lsum += __shfl_xor(lsum, off, 64);
      if ((tid & 63) == 0) red[tid >> 6] = lsum;
      __syncthreads();
      float inv = 1.f / (red[0] + red[1] + red[2] + red[3]);
      for (int i = tid; i < 300; i += 256) {
        float a = e_l[i] * inv;
        float ns = aw2[15 + i].y + a;
        aw2[15 + i] = make_float2(a, ns);
        if (s8 == 0) P.oalign[(size_t)(row * 400 + tt) * 300 + i] = a;
      }
      __syncthreads();
      {  // ctx slice: enc NT-streamed
        int j = tid & 63, pc = tid >> 6;
        float cp = 0.f;
        const float* ebase = P.enc + (size_t)(row * 300) * 512 + s8 * 64 + j;
        for (int p = pc * 75; p < pc * 75 + 75; ++p)
          cp += aw2[15 + p].x * nt_load(ebase + (size_t)p * 512);
        cpart[pc * 64 + j] = cp;
      }
      __syncthreads();
      if (tid < 64) {
        float* ctxC = P.ctx + sc * 16384;
        s_rel(&ctxC[row * 512 + s8 * 64 + tid],
              cpart[tid] + cpart[64 + tid] + cpart[128 + tid] + cpart[192 + tid]);
      }
    }
    gsync(P.arrive, P.release, ++bno, false);  // B3 (global)
  }
}

// ---- host -------------------------------------------------------------------
extern "C" void kernel_launch(void* const* d_in, const int* in_sizes, int n_in,
                              void* d_out, int out_size, void* d_ws, size_t ws_size,
                              hipStream_t stream) {
  const float* enc = (const float*)d_in[0];
  const float* mels = (const float*)d_in[1];
  const int* lens = (const int*)d_in[2];
  const float* Wp0 = (const float*)d_in[3];
  const float* Wp1 = (const float*)d_in[4];
  const float* Wp2 = (const float*)d_in[5];
  const float* Wiha = (const float*)d_in[6];
  const float* Whha = (const float*)d_in[7];
  const float* biha = (const float*)d_in[8];
  const float* bhha = (const float*)d_in[9];
  const float* Wihd = (const float*)d_in[10];
  const float* Whhd = (const float*)d_in[11];
  const float* bihd = (const float*)d_in[12];
  const float* bhhd = (const float*)d_in[13];
  const float* Wq = (const float*)d_in[14];
  const float* Wm = (const float*)d_in[15];
  const float* Kloc = (const float*)d_in[16];
  const float* Wl = (const float*)d_in[17];
  const float* vv = (const float*)d_in[18];
  const float* Wout = (const float*)d_in[19];
  const float* bout = (const float*)d_in[20];
  const float* Wg = (const float*)d_in[21];
  const float* bg = (const float*)d_in[22];

  float* ws = (float*)d_ws;
  float* x_all = ws;                    // 3,276,800
  float* pmem = x_all + 3276800;        // 1,228,800
  float* ah = pmem + 1228800;           // ring32: 524,288
  float* dh = ah + 524288;              // 524,288
  float* ctx = dh + 524288;             // 524,288
  float* e = ctx + 524288;              // 9,600
  int* arrive = (int*)(e + 9600);       // 8,192
  int* release = arrive + 8192;         // 256
  int* rarr = release + 256;            // 8,192
  int* rrel = rarr + 8192;              // 1,024

  (void)hipMemsetAsync(ah + (RING - 1) * 16384, 0, 16384 * sizeof(float), stream);
  (void)hipMemsetAsync(dh + (RING - 1) * 16384, 0, 16384 * sizeof(float), stream);
  (void)hipMemsetAsync(ctx + (RING - 1) * 16384, 0, 16384 * sizeof(float), stream);
  (void)hipMemsetAsync(arrive, 0, (8192 + 256 + 8192 + 1024) * sizeof(int), stream);

  prenet_kernel<<<800, 256, 0, stream>>>(mels, Wp0, Wp1, Wp2, x_all);
  pmem_kernel<<<320, 256, 0, stream>>>(enc, Wm, pmem);

  float* omel = (float*)d_out;                  // [32][80][400]
  float* ogate = omel + 32 * 80 * 400;          // [32][400]
  float* oalign = ogate + 32 * 400;             // [32][400][300]

  DecParams P;
  P.enc = enc; P.xall = x_all; P.pmem = pmem; P.lens = lens;
  P.Wiha = Wiha; P.Whha = Whha; P.biha = biha; P.bhha = bhha;
  P.Wihd = Wihd; P.Whhd = Whhd; P.bihd = bihd; P.bhhd = bhhd;
  P.Wq = Wq; P.Kloc = Kloc; P.Wl = Wl; P.vv = vv;
  P.Wout = Wout; P.bout = bout; P.Wg = Wg; P.bg = bg;
  P.ah = ah; P.dh = dh; P.ctx = ctx; P.e = e;
  P.arrive = arrive; P.release = release; P.rarr = rarr; P.rrel = rrel;
  P.omel = omel; P.ogate = ogate; P.oalign = oalign;

  decoder_kernel<<<NBLK, 256, 0, stream>>>(P);
}